// Round 12
// baseline (375.371 us; speedup 1.0000x reference)
//
#include <hip/hip_runtime.h>
#include <hip/hip_bf16.h>
#include <math.h>

#define D 128
#define NUM_GRAPHS 64
#define CHUNK 8192          // edges per binning block
#define BUCK_SH 8           // bucket = col >> 8  (256 nodes per bucket)
#define BUCK_N 256
#define BCAP 8192           // fixed slot capacity per bucket (mean 4096, +64 sigma)
#define PSLICE 8            // pooling blocks per graph

typedef __bf16 bf16x8 __attribute__((ext_vector_type(8)));
typedef __bf16 bf16x4 __attribute__((ext_vector_type(4)));
typedef __bf16 bf16x2 __attribute__((ext_vector_type(2)));
typedef float f32x4 __attribute__((ext_vector_type(4)));
typedef float f32x2 __attribute__((ext_vector_type(2)));

// fp8 e4m3 (OCP) helpers — HW converts on gfx950
__device__ inline unsigned char f32_to_fp8(float x) {
    int pk = __builtin_amdgcn_cvt_pk_fp8_f32(x, x, 0, false);
    return (unsigned char)(pk & 0xff);
}
__device__ inline f32x2 cvt_lo(unsigned int u) { return __builtin_amdgcn_cvt_pk_f32_fp8(u, false); }
__device__ inline f32x2 cvt_hi(unsigned int u) { return __builtin_amdgcn_cvt_pk_f32_fp8(u, true); }

// ---------------- W -> bf16 B-fragment pack; zero pooled/done/gcur; graph bounds ----------------
__global__ void k_prepW(const float* __restrict__ Wa, const float* __restrict__ Wb,
                        __bf16* __restrict__ WfA, __bf16* __restrict__ WfB,
                        float* __restrict__ pooled, int* __restrict__ done,
                        int* __restrict__ gcur,
                        const int* __restrict__ batch, int* __restrict__ gstart, int N) {
    int gid = blockIdx.x * 256 + threadIdx.x;   // 0..33023
    if (gid < NUM_GRAPHS * D) pooled[gid] = 0.f;
    if (gid == 0) *done = 0;
    if (gid < 512) gcur[gid] = 0;
    if (gid >= 16384 && gid <= 16384 + NUM_GRAPHS) {   // 65 threads do binary search
        int g = gid - 16384;
        int lo = 0, hi = N;
        while (lo < hi) { int mid = (lo + hi) >> 1; if (batch[mid] < g) lo = mid + 1; else hi = mid; }
        gstart[g] = lo;
    }
    if (gid >= 32768) return;
    const float* W = (gid < 16384) ? Wa : Wb;
    __bf16* Wf = (gid < 16384) ? WfA : WfB;
    int idx = gid & 16383;
    int j = idx & 7, lane = (idx >> 3) & 63, kc = (idx >> 9) & 3, ft = idx >> 11;
    int k = kc * 32 + (lane >> 4) * 8 + j;
    int f = ft * 16 + (lane & 15);
    Wf[idx] = (__bf16)W[k * D + f];
}

// ---------------- CSR build pass 1: bin with global range reservation ----------------
// Per block: LDS histogram of its chunk -> one global atomicAdd per bucket to
// reserve a contiguous range in the bucket's fixed slot [b*BCAP, (b+1)*BCAP) ->
// scatter (src | (col&255)<<17). No separate hist/scan kernels.
__global__ void k_bin(const int* __restrict__ ei, int* __restrict__ gcur,
                      int* __restrict__ bbuf, int nbuck, int E) {
    __shared__ int h[512];
    __shared__ int base[512];
    int tid = threadIdx.x;
    for (int b = tid; b < nbuck; b += 256) h[b] = 0;
    __syncthreads();
    int lo = blockIdx.x * CHUNK;
    for (int i = tid; i < CHUNK; i += 256) {
        int e = lo + i;
        if (e < E) atomicAdd(&h[ei[E + e] >> BUCK_SH], 1);
    }
    __syncthreads();
    for (int b = tid; b < nbuck; b += 256) {
        base[b] = atomicAdd(&gcur[b], h[b]);
        h[b] = 0;
    }
    __syncthreads();
    for (int i = tid; i < CHUNK; i += 256) {
        int e = lo + i;
        if (e < E) {
            int r = ei[e], c = ei[E + e];
            int b = c >> BUCK_SH;
            int pos = base[b] + atomicAdd(&h[b], 1);
            if (pos < BCAP) bbuf[(size_t)b * BCAP + pos] = r | ((c & (BUCK_N - 1)) << 17);
        }
    }
}

// ---------------- CSR build pass 2: per-bucket exact CSR (bucket-local bases) ----------------
// offs/esrc use bucket-fixed base b*BCAP -> no global scan needed anywhere.
__global__ void k_place(const int* __restrict__ bbuf, const int* __restrict__ gcur,
                        int* __restrict__ esrc,
                        int* __restrict__ cnt, int* __restrict__ offs,
                        float* __restrict__ dis, int N) {
    __shared__ int h[256];
    __shared__ int sc[256];
    __shared__ int cur[256];
    int b = blockIdx.x, tid = threadIdx.x;
    int start = b * BCAP;
    int count = gcur[b]; if (count > BCAP) count = BCAP;
    int end = start + count;
    h[tid] = 0;
    __syncthreads();
    for (int i = start + tid; i < end; i += 256) atomicAdd(&h[(bbuf[i] >> 17) & 255], 1);
    __syncthreads();
    int local = h[tid];
    sc[tid] = local;
    __syncthreads();
    for (int off = 1; off < 256; off <<= 1) {
        int xv = (tid >= off) ? sc[tid - off] : 0;
        __syncthreads();
        sc[tid] += xv;
        __syncthreads();
    }
    int excl = sc[tid] - local;
    cur[tid] = start + excl;
    int c = b * 256 + tid;
    if (c < N) {
        cnt[c]  = local;
        offs[c] = start + excl;
        dis[c]  = rsqrtf(1.0f + (float)local);   // deg includes self-loop
    }
    __syncthreads();
    for (int i = start + tid; i < end; i += 256) {
        int p = bbuf[i];
        int pos = atomicAdd(&cur[(p >> 17) & 255], 1);
        esrc[pos] = p & 0x1FFFF;
    }
}

// ---------------- MFMA GEMM: Y8[N,128](fp8) = dis .* (X[N,128] @ W) ----------------
template <typename T>
__launch_bounds__(256)
__global__ void k_gemm(const T* __restrict__ X, const __bf16* __restrict__ Wfrag,
                       const float* __restrict__ dis, unsigned char* __restrict__ Y8, int N) {
    int tid = threadIdx.x;
    int w = tid >> 6, lane = tid & 63;
    int quad = lane >> 4, m = lane & 15;
    int nodeA = blockIdx.x * 64 + w * 16 + m;
    if (nodeA >= N) nodeA = N - 1;

    bf16x8 a[4];
#pragma unroll
    for (int kc = 0; kc < 4; kc++) {
        int kb = kc * 32 + quad * 8;
        if constexpr (sizeof(T) == 4) {
            f32x4 x0 = *(const f32x4*)(X + (size_t)nodeA * D + kb);
            f32x4 x1 = *(const f32x4*)(X + (size_t)nodeA * D + kb + 4);
#pragma unroll
            for (int j = 0; j < 4; j++) { a[kc][j] = (__bf16)x0[j]; a[kc][4 + j] = (__bf16)x1[j]; }
        } else {
            a[kc] = *(const bf16x8*)(X + (size_t)nodeA * D + kb);
        }
    }

    f32x4 d[8];
#pragma unroll
    for (int ft = 0; ft < 8; ft++) {
        d[ft] = (f32x4){0.f, 0.f, 0.f, 0.f};
#pragma unroll
        for (int kc = 0; kc < 4; kc++) {
            bf16x8 b = *(const bf16x8*)(Wfrag + (((ft << 2) | kc) * 64 + lane) * 8);
            d[ft] = __builtin_amdgcn_mfma_f32_16x16x32_bf16(a[kc], b, d[ft], 0, 0, 0);
        }
    }

#pragma unroll
    for (int r = 0; r < 4; r++) {
        int node = blockIdx.x * 64 + w * 16 + quad * 4 + r;
        if (node < N) {
            float dv = dis[node];
#pragma unroll
            for (int ft = 0; ft < 8; ft++)
                Y8[(size_t)node * D + ft * 16 + m] = f32_to_fp8(d[ft][r] * dv);
        }
    }
}

// ---------------- CSR aggregation + bias + leaky ReLU (fp8 in, bf16 out) ----------------
// 4 feats/lane (uint = 4 fp8); the two wave-halves take alternating edges and
// are combined by one shfl_xor(32) per node -> load/shfl issue count halved
// vs 2-feat layout. 32-edge unroll keeps 16 row-gathers in flight per wave.
__launch_bounds__(256)
__global__ void k_agg(const unsigned char* __restrict__ Hs8, __bf16* __restrict__ O,
                      const int* __restrict__ offs, const int* __restrict__ cnt,
                      const float* __restrict__ dis, const int* __restrict__ esrc,
                      const float* __restrict__ bias, int N) {
    int wave = (blockIdx.x * 256 + threadIdx.x) >> 6;
    int lane = threadIdx.x & 63;
    int half = lane >> 5;            // 0: even edges, 1: odd edges
    int fl = lane & 31;              // feats 4*fl .. 4*fl+3
    int node0 = wave * 8;
    f32x4 bb = *(const f32x4*)(bias + fl * 4);

    for (int nn = 0; nn < 8; nn++) {
        int node = node0 + nn;
        if (node >= N) return;
        int start = offs[node];
        int len = cnt[node];
        float di = dis[node];
        float a0 = 0.f, a1 = 0.f, a2 = 0.f, a3 = 0.f;

        for (int k0 = 0; k0 < len; k0 += 64) {
            int mm = len - k0; if (mm > 64) mm = 64;
            int ep = esrc[start + k0 + (lane < mm ? lane : 0)];
            int j = 0;
            for (; j + 32 <= mm; j += 32) {          // 16 pairs: 16 loads in flight
                int s[16]; unsigned int hv[16];
#pragma unroll
                for (int u = 0; u < 16; u++) s[u] = __shfl(ep, j + 2 * u + half);
#pragma unroll
                for (int u = 0; u < 16; u++) hv[u] = *(const unsigned int*)(Hs8 + (size_t)s[u] * D + fl * 4);
#pragma unroll
                for (int u = 0; u < 16; u++) {
                    f32x2 f0 = cvt_lo(hv[u]), f1 = cvt_hi(hv[u]);
                    a0 += f0[0]; a1 += f0[1]; a2 += f1[0]; a3 += f1[1];
                }
            }
            for (; j + 8 <= mm; j += 8) {            // 4 pairs
                int s[4]; unsigned int hv[4];
#pragma unroll
                for (int u = 0; u < 4; u++) s[u] = __shfl(ep, j + 2 * u + half);
#pragma unroll
                for (int u = 0; u < 4; u++) hv[u] = *(const unsigned int*)(Hs8 + (size_t)s[u] * D + fl * 4);
#pragma unroll
                for (int u = 0; u < 4; u++) {
                    f32x2 f0 = cvt_lo(hv[u]), f1 = cvt_hi(hv[u]);
                    a0 += f0[0]; a1 += f0[1]; a2 += f1[0]; a3 += f1[1];
                }
            }
            for (; j < mm; j += 2) {                 // predicated tail pairs
                int jj = j + half;
                int s = __shfl(ep, jj < mm ? jj : 0);
                unsigned int hv = *(const unsigned int*)(Hs8 + (size_t)s * D + fl * 4);
                if (jj < mm) {
                    f32x2 f0 = cvt_lo(hv), f1 = cvt_hi(hv);
                    a0 += f0[0]; a1 += f0[1]; a2 += f1[0]; a3 += f1[1];
                }
            }
        }

        // combine even/odd halves
        a0 += __shfl_xor(a0, 32);
        a1 += __shfl_xor(a1, 32);
        a2 += __shfl_xor(a2, 32);
        a3 += __shfl_xor(a3, 32);
        // self-loop (already dis-scaled)
        unsigned int hs = *(const unsigned int*)(Hs8 + (size_t)node * D + fl * 4);
        f32x2 s0 = cvt_lo(hs), s1 = cvt_hi(hs);
        a0 += s0[0]; a1 += s0[1]; a2 += s1[0]; a3 += s1[1];

        a0 = a0 * di + bb[0];
        a1 = a1 * di + bb[1];
        a2 = a2 * di + bb[2];
        a3 = a3 * di + bb[3];
        a0 = a0 >= 0.f ? a0 : 0.01f * a0;
        a1 = a1 >= 0.f ? a1 : 0.01f * a1;
        a2 = a2 >= 0.f ? a2 : 0.01f * a2;
        a3 = a3 >= 0.f ? a3 : 0.01f * a3;
        if (half == 0) {
            bf16x4 o; o[0] = (__bf16)a0; o[1] = (__bf16)a1; o[2] = (__bf16)a2; o[3] = (__bf16)a3;
            *(bf16x4*)(O + (size_t)node * D + fl * 4) = o;
        }
    }
}

// ---------------- pooling: per-graph-slice vectorized reduction + fused FC ----------------
__launch_bounds__(256)
__global__ void k_pool(const __bf16* __restrict__ H, const int* __restrict__ gstart,
                       float* __restrict__ pooled,
                       const float* __restrict__ fcW, const float* __restrict__ fcb,
                       float* __restrict__ out, int* __restrict__ done) {
    __shared__ float sdata[256 * 9];
    __shared__ int lastflag;
    int g = blockIdx.x / PSLICE;
    int slice = blockIdx.x - g * PSLICE;
    int gs = gstart[g], ge = gstart[g + 1];
    int cg = ge - gs;
    int r0 = gs + (int)((long long)cg * slice / PSLICE);
    int r1 = gs + (int)((long long)cg * (slice + 1) / PSLICE);
    int t = threadIdx.x;
    int rg = t >> 4, fb = t & 15;

    float acc[8];
#pragma unroll
    for (int j = 0; j < 8; j++) acc[j] = 0.f;
    for (int r = r0 + rg; r < r1; r += 16) {
        bf16x8 v = *(const bf16x8*)(H + (size_t)r * D + fb * 8);
#pragma unroll
        for (int j = 0; j < 8; j++) acc[j] += (float)v[j];
    }
#pragma unroll
    for (int j = 0; j < 8; j++) sdata[t * 9 + j] = acc[j];
    __syncthreads();
#pragma unroll
    for (int s = 128; s >= 16; s >>= 1) {
        if (t < s) {
#pragma unroll
            for (int j = 0; j < 8; j++) sdata[t * 9 + j] += sdata[(t + s) * 9 + j];
        }
        __syncthreads();
    }
    if (t < 16) {
#pragma unroll
        for (int j = 0; j < 8; j++) atomicAdd(&pooled[g * D + t * 8 + j], sdata[t * 9 + j]);
    }
    __threadfence();
    __syncthreads();
    if (t == 0) lastflag = (atomicAdd(done, 1) == (int)gridDim.x - 1) ? 1 : 0;
    __syncthreads();
    if (lastflag) {
        __threadfence();
        if (t < NUM_GRAPHS) {
            float s = 0.f;
#pragma unroll 4
            for (int k = 0; k < D; k++) s += pooled[t * D + k] * fcW[k];
            float c = (float)(gstart[t + 1] - gstart[t]);
            out[t] = s / fmaxf(c, 1.0f) + fcb[0];
        }
    }
}

extern "C" void kernel_launch(void* const* d_in, const int* in_sizes, int n_in,
                              void* d_out, int out_size, void* d_ws, size_t ws_size,
                              hipStream_t stream) {
    const float* x    = (const float*)d_in[0];
    const int*   ei   = (const int*)d_in[1];
    const int*   batch= (const int*)d_in[2];
    const float* W1   = (const float*)d_in[3];
    const float* b1   = (const float*)d_in[4];
    const float* W2   = (const float*)d_in[5];
    const float* b2   = (const float*)d_in[6];
    const float* fcW  = (const float*)d_in[7];
    const float* fcb  = (const float*)d_in[8];
    float* out = (float*)d_out;

    int N = in_sizes[0] / D;
    int E = in_sizes[1] / 2;

    int NBUCK  = (N + BUCK_N - 1) >> BUCK_SH;  // 391 for N=100000 (<=512)
    int NCHUNK = (E + CHUNK - 1) / CHUNK;      // 196 for E=1.6M

    char* p = (char*)d_ws;
    auto alloc = [&](size_t bytes) { char* r = p; p += (bytes + 255) & ~(size_t)255; return r; };
    int*    cnt    = (int*)   alloc((size_t)N * 4);
    int*    offs   = (int*)   alloc((size_t)N * 4);
    float*  dis    = (float*) alloc((size_t)N * 4);
    int*    gcur   = (int*)   alloc(512 * 4);
    int*    bbuf   = (int*)   alloc((size_t)NBUCK * BCAP * 4);
    int*    esrc   = (int*)   alloc((size_t)NBUCK * BCAP * 4);
    unsigned char* bufA8 = (unsigned char*)alloc((size_t)N * D);   // fp8 messages
    __bf16* bufB   = (__bf16*)alloc((size_t)N * D * 2);
    __bf16* Wf1    = (__bf16*)alloc((size_t)D * D * 2);
    __bf16* Wf2    = (__bf16*)alloc((size_t)D * D * 2);
    float*  pooled = (float*) alloc((size_t)NUM_GRAPHS * D * 4);
    int*    gstart = (int*)   alloc((NUM_GRAPHS + 1) * 4);
    int*    done   = (int*)   alloc(256);

    // prep first: zeroes gcur/pooled/done, packs W, graph boundaries
    k_prepW<<<129, 256, 0, stream>>>(W1, W2, Wf1, Wf2, pooled, done, gcur, batch, gstart, N);

    // CSR build: reservation-bin -> per-bucket place (bucket-local bases)
    k_bin  <<<NCHUNK, 256, 0, stream>>>(ei, gcur, bbuf, NBUCK, E);
    k_place<<<NBUCK, 256, 0, stream>>>(bbuf, gcur, esrc, cnt, offs, dis, N);

    int gblocks = (N + 63) / 64;
    int ablocks = (N + 31) / 32;     // k_agg: 4 waves/block x 8 nodes/wave

    // layer 1: bufA8 = fp8(dis .* (x @ W1)); bufB = leaky(agg(bufA8)+b1)
    k_gemm<float><<<gblocks, 256, 0, stream>>>(x, Wf1, dis, bufA8, N);
    k_agg<<<ablocks, 256, 0, stream>>>(bufA8, bufB, offs, cnt, dis, esrc, b1, N);
    // layer 2: bufA8 = fp8(dis .* (bufB @ W2)); bufB = leaky(agg(bufA8)+b2)
    k_gemm<__bf16><<<gblocks, 256, 0, stream>>>(bufB, Wf2, dis, bufA8, N);
    k_agg<<<ablocks, 256, 0, stream>>>(bufA8, bufB, offs, cnt, dis, esrc, b2, N);
    // pool (vectorized, per-graph slices) + fused fc
    k_pool<<<NUM_GRAPHS * PSLICE, 256, 0, stream>>>(bufB, gstart, pooled, fcW, fcb, out, done);
}

// Round 13
// 313.953 us; speedup vs baseline: 1.1956x; 1.1956x over previous
//
#include <hip/hip_runtime.h>
#include <hip/hip_bf16.h>
#include <math.h>

#define D 128
#define NUM_GRAPHS 64
#define CHUNK 8192          // edges per binning block
#define BUCK_SH 8           // bucket = col >> 8  (256 nodes per bucket)
#define BUCK_N 256
#define BCAP 8192           // fixed slot capacity per bucket (mean 4096, +64 sigma)
#define PSLICE 8            // pooling blocks per graph

typedef __bf16 bf16x8 __attribute__((ext_vector_type(8)));
typedef __bf16 bf16x2 __attribute__((ext_vector_type(2)));
typedef float f32x4 __attribute__((ext_vector_type(4)));
typedef float f32x2 __attribute__((ext_vector_type(2)));

// fp8 e4m3 (OCP) helpers — HW converts on gfx950
__device__ inline unsigned char f32_to_fp8(float x) {
    int pk = __builtin_amdgcn_cvt_pk_fp8_f32(x, x, 0, false);
    return (unsigned char)(pk & 0xff);
}
__device__ inline f32x2 fp8x2_to_f32(unsigned short us) {
    return __builtin_amdgcn_cvt_pk_f32_fp8((unsigned int)us, false);
}

// ---------------- W -> bf16 B-fragment pack; zero pooled/done/gcur; graph bounds ----------------
__global__ void k_prepW(const float* __restrict__ Wa, const float* __restrict__ Wb,
                        __bf16* __restrict__ WfA, __bf16* __restrict__ WfB,
                        float* __restrict__ pooled, int* __restrict__ done,
                        int* __restrict__ gcur,
                        const int* __restrict__ batch, int* __restrict__ gstart, int N) {
    int gid = blockIdx.x * 256 + threadIdx.x;   // 0..33023
    if (gid < NUM_GRAPHS * D) pooled[gid] = 0.f;
    if (gid == 0) *done = 0;
    if (gid < 512) gcur[gid] = 0;
    if (gid >= 16384 && gid <= 16384 + NUM_GRAPHS) {   // 65 threads do binary search
        int g = gid - 16384;
        int lo = 0, hi = N;
        while (lo < hi) { int mid = (lo + hi) >> 1; if (batch[mid] < g) lo = mid + 1; else hi = mid; }
        gstart[g] = lo;
    }
    if (gid >= 32768) return;
    const float* W = (gid < 16384) ? Wa : Wb;
    __bf16* Wf = (gid < 16384) ? WfA : WfB;
    int idx = gid & 16383;
    int j = idx & 7, lane = (idx >> 3) & 63, kc = (idx >> 9) & 3, ft = idx >> 11;
    int k = kc * 32 + (lane >> 4) * 8 + j;
    int f = ft * 16 + (lane & 15);
    Wf[idx] = (__bf16)W[k * D + f];
}

// ---------------- CSR build pass 1: bin with global range reservation ----------------
// Per block: LDS histogram of its chunk (int4-vectorized reads) -> one global
// atomicAdd per bucket reserves a contiguous range in the bucket's fixed slot
// [b*BCAP,(b+1)*BCAP) -> scatter (src | (col&255)<<17).
__global__ void k_bin(const int* __restrict__ ei, int* __restrict__ gcur,
                      int* __restrict__ bbuf, int nbuck, int E) {
    __shared__ int h[512];
    __shared__ int base[512];
    int tid = threadIdx.x;
    for (int b = tid; b < nbuck; b += 256) h[b] = 0;
    __syncthreads();
    int lo = blockIdx.x * CHUNK;
    // CHUNK is a multiple of 4; guard only the block that straddles E
    if (lo + CHUNK <= E) {
        const int4* c4 = (const int4*)(ei + E + lo);
#pragma unroll 2
        for (int i = tid; i < CHUNK / 4; i += 256) {
            int4 c = c4[i];
            atomicAdd(&h[c.x >> BUCK_SH], 1);
            atomicAdd(&h[c.y >> BUCK_SH], 1);
            atomicAdd(&h[c.z >> BUCK_SH], 1);
            atomicAdd(&h[c.w >> BUCK_SH], 1);
        }
    } else {
        for (int i = tid; i < CHUNK; i += 256) {
            int e = lo + i;
            if (e < E) atomicAdd(&h[ei[E + e] >> BUCK_SH], 1);
        }
    }
    __syncthreads();
    for (int b = tid; b < nbuck; b += 256) {
        base[b] = atomicAdd(&gcur[b], h[b]);
        h[b] = 0;
    }
    __syncthreads();
    if (lo + CHUNK <= E) {
        const int4* r4 = (const int4*)(ei + lo);
        const int4* c4 = (const int4*)(ei + E + lo);
#pragma unroll 2
        for (int i = tid; i < CHUNK / 4; i += 256) {
            int4 r = r4[i];
            int4 c = c4[i];
            int rr[4] = {r.x, r.y, r.z, r.w};
            int cc[4] = {c.x, c.y, c.z, c.w};
#pragma unroll
            for (int u = 0; u < 4; u++) {
                int b = cc[u] >> BUCK_SH;
                int pos = base[b] + atomicAdd(&h[b], 1);
                if (pos < BCAP) bbuf[(size_t)b * BCAP + pos] = rr[u] | ((cc[u] & (BUCK_N - 1)) << 17);
            }
        }
    } else {
        for (int i = tid; i < CHUNK; i += 256) {
            int e = lo + i;
            if (e < E) {
                int r = ei[e], c = ei[E + e];
                int b = c >> BUCK_SH;
                int pos = base[b] + atomicAdd(&h[b], 1);
                if (pos < BCAP) bbuf[(size_t)b * BCAP + pos] = r | ((c & (BUCK_N - 1)) << 17);
            }
        }
    }
}

// ---------------- CSR build pass 2: per-bucket exact CSR (bucket-local bases) ----------------
__global__ void k_place(const int* __restrict__ bbuf, const int* __restrict__ gcur,
                        int* __restrict__ esrc,
                        int* __restrict__ cnt, int* __restrict__ offs,
                        float* __restrict__ dis, int N) {
    __shared__ int h[256];
    __shared__ int sc[256];
    __shared__ int cur[256];
    int b = blockIdx.x, tid = threadIdx.x;
    int start = b * BCAP;
    int count = gcur[b]; if (count > BCAP) count = BCAP;
    int end = start + count;
    h[tid] = 0;
    __syncthreads();
    for (int i = start + tid; i < end; i += 256) atomicAdd(&h[(bbuf[i] >> 17) & 255], 1);
    __syncthreads();
    int local = h[tid];
    sc[tid] = local;
    __syncthreads();
    for (int off = 1; off < 256; off <<= 1) {
        int xv = (tid >= off) ? sc[tid - off] : 0;
        __syncthreads();
        sc[tid] += xv;
        __syncthreads();
    }
    int excl = sc[tid] - local;
    cur[tid] = start + excl;
    int c = b * 256 + tid;
    if (c < N) {
        cnt[c]  = local;
        offs[c] = start + excl;
        dis[c]  = rsqrtf(1.0f + (float)local);   // deg includes self-loop
    }
    __syncthreads();
    for (int i = start + tid; i < end; i += 256) {
        int p = bbuf[i];
        int pos = atomicAdd(&cur[(p >> 17) & 255], 1);
        esrc[pos] = p & 0x1FFFF;
    }
}

// ---------------- MFMA GEMM: Y8[N,128](fp8) = dis .* (X[N,128] @ W) ----------------
template <typename T>
__launch_bounds__(256)
__global__ void k_gemm(const T* __restrict__ X, const __bf16* __restrict__ Wfrag,
                       const float* __restrict__ dis, unsigned char* __restrict__ Y8, int N) {
    int tid = threadIdx.x;
    int w = tid >> 6, lane = tid & 63;
    int quad = lane >> 4, m = lane & 15;
    int nodeA = blockIdx.x * 64 + w * 16 + m;
    if (nodeA >= N) nodeA = N - 1;

    bf16x8 a[4];
#pragma unroll
    for (int kc = 0; kc < 4; kc++) {
        int kb = kc * 32 + quad * 8;
        if constexpr (sizeof(T) == 4) {
            f32x4 x0 = *(const f32x4*)(X + (size_t)nodeA * D + kb);
            f32x4 x1 = *(const f32x4*)(X + (size_t)nodeA * D + kb + 4);
#pragma unroll
            for (int j = 0; j < 4; j++) { a[kc][j] = (__bf16)x0[j]; a[kc][4 + j] = (__bf16)x1[j]; }
        } else {
            a[kc] = *(const bf16x8*)(X + (size_t)nodeA * D + kb);
        }
    }

    f32x4 d[8];
#pragma unroll
    for (int ft = 0; ft < 8; ft++) {
        d[ft] = (f32x4){0.f, 0.f, 0.f, 0.f};
#pragma unroll
        for (int kc = 0; kc < 4; kc++) {
            bf16x8 b = *(const bf16x8*)(Wfrag + (((ft << 2) | kc) * 64 + lane) * 8);
            d[ft] = __builtin_amdgcn_mfma_f32_16x16x32_bf16(a[kc], b, d[ft], 0, 0, 0);
        }
    }

#pragma unroll
    for (int r = 0; r < 4; r++) {
        int node = blockIdx.x * 64 + w * 16 + quad * 4 + r;
        if (node < N) {
            float dv = dis[node];
#pragma unroll
            for (int ft = 0; ft < 8; ft++)
                Y8[(size_t)node * D + ft * 16 + m] = f32_to_fp8(d[ft][r] * dv);
        }
    }
}

// ---------------- CSR aggregation + bias + leaky ReLU (fp8 in, bf16 out) ----------------
// R11 layout (measured 54 us): lane owns feats (2*lane, 2*lane+1) = one ushort
// per row -> each load instruction gathers ONE full 128B row coalesced. One
// wave per 8 consecutive nodes; meta preloaded 64-wide + shfl; x16 unroll.
__launch_bounds__(256)
__global__ void k_agg(const unsigned char* __restrict__ Hs8, __bf16* __restrict__ O,
                      const int* __restrict__ offs, const int* __restrict__ cnt,
                      const float* __restrict__ dis, const int* __restrict__ esrc,
                      const float* __restrict__ bias, int N) {
    int wave = (blockIdx.x * 256 + threadIdx.x) >> 6;
    int lane = threadIdx.x & 63;
    int node0 = wave * 8;
    float b0 = bias[lane * 2], b1 = bias[lane * 2 + 1];

    for (int nn = 0; nn < 8; nn++) {
        int node = node0 + nn;
        if (node >= N) return;
        int start = offs[node];
        int len = cnt[node];
        float di = dis[node];
        f32x2 h = fp8x2_to_f32(*(const unsigned short*)(Hs8 + (size_t)node * D + lane * 2));
        float acc0 = h[0];               // self-loop term (already dis-scaled)
        float acc1 = h[1];

        for (int k0 = 0; k0 < len; k0 += 64) {
            int mm = len - k0; if (mm > 64) mm = 64;
            int ep = esrc[start + k0 + (lane < mm ? lane : 0)];
            int j = 0;
            for (; j + 16 <= mm; j += 16) {
                int s[16]; unsigned short hv[16];
#pragma unroll
                for (int u = 0; u < 16; u++) s[u] = __shfl(ep, j + u);
#pragma unroll
                for (int u = 0; u < 16; u++) hv[u] = *(const unsigned short*)(Hs8 + (size_t)s[u] * D + lane * 2);
#pragma unroll
                for (int u = 0; u < 16; u++) { f32x2 f = fp8x2_to_f32(hv[u]); acc0 += f[0]; acc1 += f[1]; }
            }
            for (; j + 4 <= mm; j += 4) {
                int s[4]; unsigned short hv[4];
#pragma unroll
                for (int u = 0; u < 4; u++) s[u] = __shfl(ep, j + u);
#pragma unroll
                for (int u = 0; u < 4; u++) hv[u] = *(const unsigned short*)(Hs8 + (size_t)s[u] * D + lane * 2);
#pragma unroll
                for (int u = 0; u < 4; u++) { f32x2 f = fp8x2_to_f32(hv[u]); acc0 += f[0]; acc1 += f[1]; }
            }
            for (; j < mm; j++) {
                int s = __shfl(ep, j);
                f32x2 f = fp8x2_to_f32(*(const unsigned short*)(Hs8 + (size_t)s * D + lane * 2));
                acc0 += f[0]; acc1 += f[1];
            }
        }

        acc0 = acc0 * di + b0;
        acc1 = acc1 * di + b1;
        acc0 = acc0 >= 0.f ? acc0 : 0.01f * acc0;
        acc1 = acc1 >= 0.f ? acc1 : 0.01f * acc1;
        bf16x2 o; o[0] = (__bf16)acc0; o[1] = (__bf16)acc1;
        *(bf16x2*)(O + (size_t)node * D + lane * 2) = o;
    }
}

// ---------------- pooling: per-graph-slice vectorized reduction + fused FC ----------------
__launch_bounds__(256)
__global__ void k_pool(const __bf16* __restrict__ H, const int* __restrict__ gstart,
                       float* __restrict__ pooled,
                       const float* __restrict__ fcW, const float* __restrict__ fcb,
                       float* __restrict__ out, int* __restrict__ done) {
    __shared__ float sdata[256 * 9];
    __shared__ int lastflag;
    int g = blockIdx.x / PSLICE;
    int slice = blockIdx.x - g * PSLICE;
    int gs = gstart[g], ge = gstart[g + 1];
    int cg = ge - gs;
    int r0 = gs + (int)((long long)cg * slice / PSLICE);
    int r1 = gs + (int)((long long)cg * (slice + 1) / PSLICE);
    int t = threadIdx.x;
    int rg = t >> 4, fb = t & 15;

    float acc[8];
#pragma unroll
    for (int j = 0; j < 8; j++) acc[j] = 0.f;
    for (int r = r0 + rg; r < r1; r += 16) {
        bf16x8 v = *(const bf16x8*)(H + (size_t)r * D + fb * 8);
#pragma unroll
        for (int j = 0; j < 8; j++) acc[j] += (float)v[j];
    }
#pragma unroll
    for (int j = 0; j < 8; j++) sdata[t * 9 + j] = acc[j];
    __syncthreads();
#pragma unroll
    for (int s = 128; s >= 16; s >>= 1) {
        if (t < s) {
#pragma unroll
            for (int j = 0; j < 8; j++) sdata[t * 9 + j] += sdata[(t + s) * 9 + j];
        }
        __syncthreads();
    }
    if (t < 16) {
#pragma unroll
        for (int j = 0; j < 8; j++) atomicAdd(&pooled[g * D + t * 8 + j], sdata[t * 9 + j]);
    }
    __threadfence();
    __syncthreads();
    if (t == 0) lastflag = (atomicAdd(done, 1) == (int)gridDim.x - 1) ? 1 : 0;
    __syncthreads();
    if (lastflag) {
        __threadfence();
        if (t < NUM_GRAPHS) {
            float s = 0.f;
#pragma unroll 4
            for (int k = 0; k < D; k++) s += pooled[t * D + k] * fcW[k];
            float c = (float)(gstart[t + 1] - gstart[t]);
            out[t] = s / fmaxf(c, 1.0f) + fcb[0];
        }
    }
}

extern "C" void kernel_launch(void* const* d_in, const int* in_sizes, int n_in,
                              void* d_out, int out_size, void* d_ws, size_t ws_size,
                              hipStream_t stream) {
    const float* x    = (const float*)d_in[0];
    const int*   ei   = (const int*)d_in[1];
    const int*   batch= (const int*)d_in[2];
    const float* W1   = (const float*)d_in[3];
    const float* b1   = (const float*)d_in[4];
    const float* W2   = (const float*)d_in[5];
    const float* b2   = (const float*)d_in[6];
    const float* fcW  = (const float*)d_in[7];
    const float* fcb  = (const float*)d_in[8];
    float* out = (float*)d_out;

    int N = in_sizes[0] / D;
    int E = in_sizes[1] / 2;

    int NBUCK  = (N + BUCK_N - 1) >> BUCK_SH;  // 391 for N=100000 (<=512)
    int NCHUNK = (E + CHUNK - 1) / CHUNK;      // 196 for E=1.6M

    char* p = (char*)d_ws;
    auto alloc = [&](size_t bytes) { char* r = p; p += (bytes + 255) & ~(size_t)255; return r; };
    int*    cnt    = (int*)   alloc((size_t)N * 4);
    int*    offs   = (int*)   alloc((size_t)N * 4);
    float*  dis    = (float*) alloc((size_t)N * 4);
    int*    gcur   = (int*)   alloc(512 * 4);
    int*    bbuf   = (int*)   alloc((size_t)NBUCK * BCAP * 4);
    int*    esrc   = (int*)   alloc((size_t)NBUCK * BCAP * 4);
    unsigned char* bufA8 = (unsigned char*)alloc((size_t)N * D);   // fp8 messages
    __bf16* bufB   = (__bf16*)alloc((size_t)N * D * 2);
    __bf16* Wf1    = (__bf16*)alloc((size_t)D * D * 2);
    __bf16* Wf2    = (__bf16*)alloc((size_t)D * D * 2);
    float*  pooled = (float*) alloc((size_t)NUM_GRAPHS * D * 4);
    int*    gstart = (int*)   alloc((NUM_GRAPHS + 1) * 4);
    int*    done   = (int*)   alloc(256);

    // prep first: zeroes gcur/pooled/done, packs W, graph boundaries
    k_prepW<<<129, 256, 0, stream>>>(W1, W2, Wf1, Wf2, pooled, done, gcur, batch, gstart, N);

    // CSR build: reservation-bin -> per-bucket place (bucket-local bases)
    k_bin  <<<NCHUNK, 256, 0, stream>>>(ei, gcur, bbuf, NBUCK, E);
    k_place<<<NBUCK, 256, 0, stream>>>(bbuf, gcur, esrc, cnt, offs, dis, N);

    int gblocks = (N + 63) / 64;
    int ablocks = (N + 31) / 32;     // k_agg: 4 waves/block x 8 nodes/wave

    // layer 1: bufA8 = fp8(dis .* (x @ W1)); bufB = leaky(agg(bufA8)+b1)
    k_gemm<float><<<gblocks, 256, 0, stream>>>(x, Wf1, dis, bufA8, N);
    k_agg<<<ablocks, 256, 0, stream>>>(bufA8, bufB, offs, cnt, dis, esrc, b1, N);
    // layer 2: bufA8 = fp8(dis .* (bufB @ W2)); bufB = leaky(agg(bufA8)+b2)
    k_gemm<__bf16><<<gblocks, 256, 0, stream>>>(bufB, Wf2, dis, bufA8, N);
    k_agg<<<ablocks, 256, 0, stream>>>(bufA8, bufB, offs, cnt, dis, esrc, b2, N);
    // pool (vectorized, per-graph slices) + fused fc
    k_pool<<<NUM_GRAPHS * PSLICE, 256, 0, stream>>>(bufB, gstart, pooled, fcW, fcb, out, done);
}